// Round 11
// baseline (840.798 us; speedup 1.0000x reference)
//
#include <hip/hip_runtime.h>
#include <stdint.h>

#define TPB 128
typedef unsigned short u16;
typedef unsigned int u32;
using short8 = __attribute__((ext_vector_type(8))) short;
using f32x16 = __attribute__((ext_vector_type(16))) float;

__device__ __forceinline__ float sigf(float x){
  return __builtin_amdgcn_rcpf(1.0f + __expf(-x));
}
__device__ __forceinline__ float tanh_f(float x){
  return 1.0f - 2.0f*__builtin_amdgcn_rcpf(1.0f + __expf(2.0f*x));
}
__device__ __forceinline__ u16 f2bf(float f){
  u32 u = __float_as_uint(f);
  u += 0x7FFFu + ((u>>16)&1u);
  return (u16)(u>>16);
}
__device__ __forceinline__ float bf2f(u16 h){ return __uint_as_float(((u32)h)<<16); }

// ---------------- CSR build ----------------
__global__ void k_deg(const int* __restrict__ dst, int* __restrict__ deg, int E){
  int i = blockIdx.x*256 + threadIdx.x;
  if (i < E) atomicAdd(&deg[dst[i]], 1);
}

__global__ __launch_bounds__(256) void k_scan1(const int* __restrict__ deg, int* __restrict__ indptr,
                                               int* __restrict__ bsum, int N){
  __shared__ int s[256];
  int tid = threadIdx.x;
  int i = blockIdx.x*256 + tid;
  int v = (i < N) ? deg[i] : 0;
  s[tid] = v; __syncthreads();
  for (int off=1; off<256; off<<=1){
    int t = (tid>=off) ? s[tid-off] : 0;
    __syncthreads();
    s[tid] += t;
    __syncthreads();
  }
  if (i < N) indptr[i] = s[tid] - v;
  if (tid == 255) bsum[blockIdx.x] = s[255];
}

__global__ __launch_bounds__(512) void k_scan2(const int* __restrict__ bsum, int* __restrict__ boffs,
                                               int* __restrict__ indptr, int nb, int N){
  __shared__ int s[512];
  int tid = threadIdx.x;
  int v = (tid < nb) ? bsum[tid] : 0;
  s[tid] = v; __syncthreads();
  for (int off=1; off<512; off<<=1){
    int t = (tid>=off) ? s[tid-off] : 0;
    __syncthreads();
    s[tid] += t;
    __syncthreads();
  }
  boffs[tid] = s[tid] - v;
  if (tid == nb-1) indptr[N] = s[tid];
}

__global__ __launch_bounds__(256) void k_scan3(int* __restrict__ indptr, const int* __restrict__ boffs, int N){
  int i = blockIdx.x*256 + threadIdx.x;
  if (i < N) indptr[i] += boffs[blockIdx.x];
}

__global__ void k_fill(const int* __restrict__ src, const int* __restrict__ dst,
                       const int* __restrict__ indptr, int* __restrict__ fill,
                       int* __restrict__ col, int E){
  int i = blockIdx.x*256 + threadIdx.x;
  if (i < E){
    int d = dst[i];
    int r = atomicAdd(&fill[d], 1);
    col[indptr[d] + r] = src[i];
  }
}

// ---------------- aggregation: z[n] = relu( y[n] + sum_{nbr} y[src] + bias ) ----------------
template<int F>
__global__ __launch_bounds__(256) void k_agg(const float* __restrict__ y, const int* __restrict__ indptr,
                                             const int* __restrict__ col, const float* __restrict__ bias,
                                             float* __restrict__ z, int N){
  constexpr int TPN = F/4;
  constexpr int NPB = 256/TPN;
  int n = blockIdx.x*NPB + threadIdx.x/TPN;
  int lane = threadIdx.x % TPN;
  if (n >= N) return;
  const float4* hv = (const float4*)y;
  float4 acc = hv[(size_t)n*TPN + lane];
  int s = indptr[n], e = indptr[n+1];
  int p = s;
  for (; p + 8 <= e; p += 8){
    int c8[8];
    #pragma unroll
    for (int i=0;i<8;++i) c8[i] = col[p+i];
    #pragma unroll
    for (int i=0;i<8;++i){
      float4 x = hv[(size_t)c8[i]*TPN + lane];
      acc.x += x.x; acc.y += x.y; acc.z += x.z; acc.w += x.w;
    }
  }
  for (; p < e; ++p){
    float4 x = hv[(size_t)col[p]*TPN + lane];
    acc.x += x.x; acc.y += x.y; acc.z += x.z; acc.w += x.w;
  }
  float4 b4 = ((const float4*)bias)[lane];
  acc.x = fmaxf(acc.x + b4.x, 0.f);
  acc.y = fmaxf(acc.y + b4.y, 0.f);
  acc.z = fmaxf(acc.z + b4.z, 0.f);
  acc.w = fmaxf(acc.w + b4.w, 0.f);
  ((float4*)z)[(size_t)n*TPN + lane] = acc;
}

// ---------------- generic f32 GEMM ----------------
__global__ __launch_bounds__(TPB) void k_gemm(const float* __restrict__ A, const float* __restrict__ W,
                                              const float* __restrict__ bias, float* __restrict__ out,
                                              int K, int JC, int act, int N){
  extern __shared__ float sm[];
  float* As = sm;
  float* Ws = sm + (size_t)K*68;
  const int tid = threadIdx.x;
  const int tx = tid & 15, ty = tid >> 4;
  const int nb = blockIdx.x * 64;
  const int kq = K >> 2;
  for (int it = 0, idx = tid; it < (kq >> 1); ++it, idx += TPB){
    int nl = idx & 63, kk = idx >> 6;
    int k4 = kk << 2;
    int n = nb + nl;
    float4 v = make_float4(0.f,0.f,0.f,0.f);
    if (n < N) v = *(const float4*)(A + (size_t)n*K + k4);
    As[(size_t)(k4+0)*68 + nl] = v.x;
    As[(size_t)(k4+1)*68 + nl] = v.y;
    As[(size_t)(k4+2)*68 + nl] = v.z;
    As[(size_t)(k4+3)*68 + nl] = v.w;
  }
  const int ncc = JC >> 5;
  for (int cc = 0; cc < ncc; ++cc){
    __syncthreads();
    for (int it = 0, idx = tid; it < (kq >> 2); ++it, idx += TPB){
      int cl = idx & 31, kk = idx >> 5;
      int k4 = kk << 2;
      int j = (cc << 5) + cl;
      float4 v = *(const float4*)(W + (size_t)j*K + k4);
      Ws[(size_t)(k4+0)*34 + cl] = v.x;
      Ws[(size_t)(k4+1)*34 + cl] = v.y;
      Ws[(size_t)(k4+2)*34 + cl] = v.z;
      Ws[(size_t)(k4+3)*34 + cl] = v.w;
    }
    __syncthreads();
    float4 acc0 = make_float4(0,0,0,0), acc1 = acc0, acc2 = acc0, acc3 = acc0;
    #pragma unroll 4
    for (int k = 0; k < K; ++k){
      float4 a = *(const float4*)(As + (size_t)k*68 + (tx<<2));
      float2 w01 = *(const float2*)(Ws + (size_t)k*34 + (ty<<2));
      float2 w23 = *(const float2*)(Ws + (size_t)k*34 + (ty<<2) + 2);
      acc0.x = fmaf(a.x, w01.x, acc0.x); acc0.y = fmaf(a.x, w01.y, acc0.y);
      acc0.z = fmaf(a.x, w23.x, acc0.z); acc0.w = fmaf(a.x, w23.y, acc0.w);
      acc1.x = fmaf(a.y, w01.x, acc1.x); acc1.y = fmaf(a.y, w01.y, acc1.y);
      acc1.z = fmaf(a.y, w23.x, acc1.z); acc1.w = fmaf(a.y, w23.y, acc1.w);
      acc2.x = fmaf(a.z, w01.x, acc2.x); acc2.y = fmaf(a.z, w01.y, acc2.y);
      acc2.z = fmaf(a.z, w23.x, acc2.z); acc2.w = fmaf(a.z, w23.y, acc2.w);
      acc3.x = fmaf(a.w, w01.x, acc3.x); acc3.y = fmaf(a.w, w01.y, acc3.y);
      acc3.z = fmaf(a.w, w23.x, acc3.z); acc3.w = fmaf(a.w, w23.y, acc3.w);
    }
    int j0 = (cc << 5) + (ty << 2);
    float4 b4 = make_float4(0,0,0,0);
    if (bias) b4 = *(const float4*)(bias + j0);
    float4 r[4] = {acc0, acc1, acc2, acc3};
    #pragma unroll
    for (int i = 0; i < 4; ++i){
      int n = nb + (tx<<2) + i;
      if (n < N){
        float4 o;
        o.x = r[i].x + b4.x; o.y = r[i].y + b4.y; o.z = r[i].z + b4.z; o.w = r[i].w + b4.w;
        if (act){
          o.x = fmaxf(o.x, 0.f); o.y = fmaxf(o.y, 0.f);
          o.z = fmaxf(o.z, 0.f); o.w = fmaxf(o.w, 0.f);
        }
        *(float4*)(out + (size_t)n*JC + j0) = o;
      }
    }
  }
}

// ---------------- LSTM weight prepack v6: fragment-linear bf16, j-consecutive row map ----------------
// Row r = rt*32 + rl, rl = q + 8*rg + 4*hi  ->  gate q, j = rt*8 + hi*4 + rg.
// Wp index = ((kt*12 + rt)*64 + l)*8 + i
__global__ __launch_bounds__(256) void k_packW2(const float* __restrict__ Wih, const float* __restrict__ Whh,
                                                u16* __restrict__ Wp){
  int idx = blockIdx.x*256 + threadIdx.x;
  if (idx >= 10*12*64*8) return;
  int i  = idx & 7;
  int l  = (idx>>3) & 63;
  int rt = (idx>>9) % 12;
  int kt = (idx>>9) / 12;
  int rl = l & 31;
  int q  = rl & 3;
  int hi = (rl >> 2) & 1;
  int rg = rl >> 3;
  int j  = rt*8 + hi*4 + rg;
  int row = q*96 + j;
  int k  = kt*16 + ((l>>5)<<3) + i;
  float v = (k < 64) ? Wih[row*64 + k] : Whh[row*96 + (k-64)];
  Wp[idx] = f2bf(v);
}

__global__ __launch_bounds__(128) void k_packB(const float* __restrict__ bih, const float* __restrict__ bhh,
                                               float4* __restrict__ Bp){
  int j = blockIdx.x*128 + threadIdx.x;
  if (j >= 96) return;
  Bp[j] = make_float4(bih[j]+bhh[j], bih[96+j]+bhh[96+j],
                      bih[192+j]+bhh[192+j], bih[288+j]+bhh[288+j]);
}

// ---------------- MFMA LSTM v6: direct b64 h-writeback, no hF/restage ----------------
// 256 thr / 4 waves (wave = rtg) / 32 nodes. X planes XH/XL: [kt(0..9)][slot(64)][8] u16,
// slot XOR-swizzled by (kt*2+hi)&7; kt 0..3 = x, kt 4..9 = h. 20 KB total LDS planes.
// Epilogue packs 4 consecutive j (j = j8*8 + hi*4 + rg) -> one uint2 write per plane per ti
// (2 lanes/bank = conflict-free). Intra-step barrier closes h-reads before overwrite.

__device__ __forceinline__ void ldx_regs(const float* __restrict__ seq, int blk, int N, int tid,
                                         float (&v)[8]){
  int node = tid >> 3;         // 0..31
  int kc = tid & 7;
  int n = blk*32 + node;
  if (n < N){
    const float4* s4 = (const float4*)(seq + (size_t)n*64 + kc*8);
    float4 a = s4[0], b = s4[1];
    v[0]=a.x; v[1]=a.y; v[2]=a.z; v[3]=a.w; v[4]=b.x; v[5]=b.y; v[6]=b.z; v[7]=b.w;
  } else {
    #pragma unroll
    for (int i=0;i<8;++i) v[i]=0.f;
  }
}

__device__ __forceinline__ void cvt8p(const float (&v)[8], u32 (&hw)[4], u32 (&lw)[4]){
  #pragma unroll
  for (int i=0;i<4;++i){
    u16 h0=f2bf(v[2*i]),   h1=f2bf(v[2*i+1]);
    u16 l0=f2bf(v[2*i]-bf2f(h0)), l1=f2bf(v[2*i+1]-bf2f(h1));
    hw[i]= (u32)h0 | ((u32)h1<<16);
    lw[i]= (u32)l0 | ((u32)l1<<16);
  }
}

__device__ __forceinline__ void stage_from_regs(const float (&v)[8], u16* __restrict__ XH,
                                                u16* __restrict__ XL, int tid){
  int node = tid >> 3;
  int kc = tid & 7;            // kc = kt*2 + hi
  u32 hw[4], lw[4];
  cvt8p(v, hw, lw);
  int kt = kc >> 1, hi = kc & 1;
  int sl = (((hi<<5) | node) ^ (kc & 7));
  int addr = (kt<<9) + (sl<<3);
  *(uint4*)(XH + addr) = make_uint4(hw[0],hw[1],hw[2],hw[3]);
  *(uint4*)(XL + addr) = make_uint4(lw[0],lw[1],lw[2],lw[3]);
}

template<int FIRST, int WRITEH>
__device__ __forceinline__ float lstm_step6(const u16* __restrict__ Wp,
    const float4* __restrict__ Bp, const float* __restrict__ WattW,
    u16* __restrict__ XH, u16* __restrict__ XL,
    float (&c)[12], int rtg, int l)
{
  constexpr int NKT = FIRST ? 4 : 10;
  const int hi = l >> 5;
  const int col = l & 31;
  f32x16 acc[3];
  #pragma unroll
  for (int t=0;t<3;++t)
    #pragma unroll
    for (int r=0;r<16;++r) acc[t][r] = 0.f;

  const u16* wbase = Wp + (size_t)(rtg*3)*512 + ((size_t)l<<3);
  #pragma unroll
  for (int kt = 0; kt < NKT; ++kt){
    const u16* wk = wbase + (size_t)kt*6144;
    short8 A0 = *(const short8*)(wk);
    short8 A1 = *(const short8*)(wk + 512);
    short8 A2 = *(const short8*)(wk + 1024);
    int sl = l ^ (((kt<<1) + hi) & 7);
    int baddr = (kt<<9) + (sl<<3);
    short8 Bh = *(const short8*)(XH + baddr);
    short8 Bl = *(const short8*)(XL + baddr);
    __builtin_amdgcn_s_setprio(1);
    acc[0] = __builtin_amdgcn_mfma_f32_32x32x16_bf16(A0, Bh, acc[0], 0,0,0);
    acc[1] = __builtin_amdgcn_mfma_f32_32x32x16_bf16(A1, Bh, acc[1], 0,0,0);
    acc[2] = __builtin_amdgcn_mfma_f32_32x32x16_bf16(A2, Bh, acc[2], 0,0,0);
    acc[0] = __builtin_amdgcn_mfma_f32_32x32x16_bf16(A0, Bl, acc[0], 0,0,0);
    acc[1] = __builtin_amdgcn_mfma_f32_32x32x16_bf16(A1, Bl, acc[1], 0,0,0);
    acc[2] = __builtin_amdgcn_mfma_f32_32x32x16_bf16(A2, Bl, acc[2], 0,0,0);
    __builtin_amdgcn_s_setprio(0);
  }

  if (!FIRST && WRITEH) __syncthreads();   // all waves done reading h before overwrite

  float aP = 0.f;
  #pragma unroll
  for (int ti=0;ti<3;++ti){
    const int j8 = rtg*3 + ti;
    const int j0 = j8*8 + hi*4;
    float hv4[4];
    #pragma unroll
    for (int rg=0; rg<4; ++rg){
      const int j = j0 + rg;
      float4 bv = Bp[j];
      float gi = acc[ti][rg*4+0] + bv.x;
      float gf = acc[ti][rg*4+1] + bv.y;
      float gg = acc[ti][rg*4+2] + bv.z;
      float go = acc[ti][rg*4+3] + bv.w;
      const int ci = ti*4 + rg;
      float cp = FIRST ? 0.f : c[ci];
      float cn = sigf(gf)*cp + sigf(gi)*tanh_f(gg);
      float hh = sigf(go)*tanh_f(cn);
      c[ci] = cn;
      aP = fmaf(hh, WattW[j], aP);
      hv4[rg] = hh;
    }
    if (WRITEH){
      u16 hb0=f2bf(hv4[0]), hb1=f2bf(hv4[1]), hb2=f2bf(hv4[2]), hb3=f2bf(hv4[3]);
      u16 lb0=f2bf(hv4[0]-bf2f(hb0)), lb1=f2bf(hv4[1]-bf2f(hb1));
      u16 lb2=f2bf(hv4[2]-bf2f(hb2)), lb3=f2bf(hv4[3]-bf2f(hb3));
      const int ktG = 4 + (j8>>1);
      const int hik = j8 & 1;
      const int sl = (((hik<<5) | col) ^ (((ktG<<1)|hik) & 7));
      const int addr = (ktG<<9) + (sl<<3) + (hi<<2);
      *(uint2*)(XH + addr) = make_uint2((u32)hb0 | ((u32)hb1<<16), (u32)hb2 | ((u32)hb3<<16));
      *(uint2*)(XL + addr) = make_uint2((u32)lb0 | ((u32)lb1<<16), (u32)lb2 | ((u32)lb3<<16));
    }
  }
  return aP;
}

__global__ __launch_bounds__(256,2) void k_lstm6(
    const float* __restrict__ h1, const float* __restrict__ h2, const float* __restrict__ h3,
    const u16* __restrict__ Wpf, const u16* __restrict__ Wpb,
    const float4* __restrict__ Bpf, const float4* __restrict__ Bpb,
    const float* __restrict__ Watt, const float* __restrict__ batt,
    float* __restrict__ aF, float* __restrict__ aB, int gL, int N)
{
  __shared__ u16 XH[5120];
  __shared__ u16 XL[5120];
  __shared__ float sAl[4][3][32];
  const int tid = threadIdx.x;
  const int l = tid & 63;
  const int rtg = __builtin_amdgcn_readfirstlane(tid >> 6);
  const int dir = (blockIdx.x >= gL) ? 1 : 0;
  const int blk = blockIdx.x - dir*gL;
  const float* sA = dir ? h3 : h1;
  const float* sC = dir ? h1 : h3;
  const u16* Wp = dir ? Wpb : Wpf;
  const float4* Bp = dir ? Bpb : Bpf;
  const float* WattW = Watt + dir*96;
  float* aD = dir ? aB : aF;
  float c[12];
  float a0, a1, a2;
  float xv[8];

  // prologue: stage x0; pre-issue x1 loads
  ldx_regs(sA, blk, N, tid, xv);
  stage_from_regs(xv, XH, XL, tid);
  ldx_regs(h2, blk, N, tid, xv);
  __syncthreads();

  a0 = lstm_step6<1,1>(Wp, Bp, WattW, XH, XL, c, rtg, l);   // epi writes h (x-only readers: safe)
  __syncthreads();                                           // close MFMA0 x-reads, publish h
  stage_from_regs(xv, XH, XL, tid);
  ldx_regs(sC, blk, N, tid, xv);
  __syncthreads();                                           // publish x1

  a1 = lstm_step6<0,1>(Wp, Bp, WattW, XH, XL, c, rtg, l);   // internal bar before epi h-write
  stage_from_regs(xv, XH, XL, tid);                          // x2: MFMA1 x-reads closed by internal bar
  __syncthreads();                                           // publish x2 + epi1 h

  a2 = lstm_step6<0,0>(Wp, Bp, WattW, XH, XL, c, rtg, l);

  // alpha reduce: lanes l and l^32 hold complementary gate halves of same node
  a0 += __shfl_xor(a0, 32);
  a1 += __shfl_xor(a1, 32);
  a2 += __shfl_xor(a2, 32);
  if (l < 32){
    sAl[rtg][0][l] = a0;
    sAl[rtg][1][l] = a1;
    sAl[rtg][2][l] = a2;
  }
  __syncthreads();
  if (tid < 96){
    int s = tid >> 5;
    int node = tid & 31;
    int n = blk*32 + node;
    if (n < N){
      float sum = sAl[0][s][node] + sAl[1][s][node]
                + sAl[2][s][node] + sAl[3][s][node];
      int slice = dir ? (2 - s) : s;
      float v = dir ? sum : (batt[0] + sum);
      aD[(size_t)slice*N + n] = v;
    }
  }
}

// ---------------- JK softmax + xjk + Wlin + Wfc1 + leaky (64 nodes/block) ----------------
__global__ __launch_bounds__(256) void k_jk(const float* __restrict__ aF, const float* __restrict__ aB,
                                            const float* __restrict__ h1, const float* __restrict__ h2,
                                            const float* __restrict__ h3,
                                            const float* __restrict__ Wlin, const float* __restrict__ blin,
                                            const float* __restrict__ Wfc1, const float* __restrict__ bfc1,
                                            float* __restrict__ vout, int N){
  __shared__ float sWl[64*65];
  __shared__ float sX[4][64];
  int tid = threadIdx.x;
  for (int idx = tid; idx < 1024; idx += 256){
    int j = idx >> 4;
    int c4 = (idx & 15) << 2;
    float4 v = *(const float4*)(Wlin + (size_t)j*64 + c4);
    sWl[j*65 + c4+0] = v.x; sWl[j*65 + c4+1] = v.y;
    sWl[j*65 + c4+2] = v.z; sWl[j*65 + c4+3] = v.w;
  }
  __syncthreads();
  int ln = tid >> 6, j = tid & 63;
  float wf1 = Wfc1[j];
  float bl = blin[j];
  for (int ib = 0; ib < 16; ++ib){
    int n = blockIdx.x*64 + ib*4 + ln;
    bool ok = n < N;
    float xj = 0.f;
    if (ok){
      float a0 = aF[n] + aB[n];
      float a1 = aF[(size_t)N + n] + aB[(size_t)N + n];
      float a2 = aF[(size_t)2*N + n] + aB[(size_t)2*N + n];
      float m = fmaxf(a0, fmaxf(a1, a2));
      float e0 = __expf(a0-m), e1 = __expf(a1-m), e2 = __expf(a2-m);
      float inv = __builtin_amdgcn_rcpf(e0+e1+e2);
      float w0 = e0*inv, w1 = e1*inv, w2 = e2*inv;
      xj = w0*h1[(size_t)n*64 + j] + w1*h2[(size_t)n*64 + j] + w2*h3[(size_t)n*64 + j];
    }
    sX[ln][j] = xj;
    __syncthreads();
    float acc = bl;
    #pragma unroll 8
    for (int cc = 0; cc < 64; ++cc) acc = fmaf(sX[ln][cc], sWl[j*65 + cc], acc);
    float r = acc * wf1;
    #pragma unroll
    for (int off = 32; off > 0; off >>= 1) r += __shfl_down(r, off);
    if (j == 0 && ok){
      float vv = r + bfc1[0];
      vout[n] = vv >= 0.f ? vv : 0.01f*vv;
    }
    __syncthreads();
  }
}

// ---------------- final dot (deterministic two-stage, f64 accum) ----------------
__global__ __launch_bounds__(256) void k_final1(const float* __restrict__ w, const float* __restrict__ v,
                                                double* __restrict__ part, int N){
  __shared__ double sd[256];
  int tid = threadIdx.x;
  double a = 0.0;
  for (int i = blockIdx.x*256 + tid; i < N; i += 256*256)
    a += (double)(w[i] * v[i]);
  sd[tid] = a; __syncthreads();
  for (int off = 128; off > 0; off >>= 1){
    if (tid < off) sd[tid] += sd[tid + off];
    __syncthreads();
  }
  if (tid == 0) part[blockIdx.x] = sd[0];
}

__global__ __launch_bounds__(256) void k_final2(const double* __restrict__ part, const float* __restrict__ bfc2,
                                                float* __restrict__ out){
  __shared__ double sd[256];
  int tid = threadIdx.x;
  sd[tid] = part[tid]; __syncthreads();
  for (int off = 128; off > 0; off >>= 1){
    if (tid < off) sd[tid] += sd[tid + off];
    __syncthreads();
  }
  if (tid == 0) out[0] = (float)(sd[0] + (double)bfc2[0]);
}

// ---------------- host ----------------
extern "C" void kernel_launch(void* const* d_in, const int* in_sizes, int n_in,
                              void* d_out, int out_size, void* d_ws, size_t ws_size,
                              hipStream_t stream){
  const float* x    = (const float*)d_in[0];
  const int*   ei   = (const int*)d_in[1];
  const float* W0a  = (const float*)d_in[2];
  const float* b0a  = (const float*)d_in[3];
  const float* W0b  = (const float*)d_in[4];
  const float* b0b  = (const float*)d_in[5];
  const float* W1a  = (const float*)d_in[6];
  const float* b1a  = (const float*)d_in[7];
  const float* W1b  = (const float*)d_in[8];
  const float* b1b  = (const float*)d_in[9];
  const float* W2a  = (const float*)d_in[10];
  const float* b2a  = (const float*)d_in[11];
  const float* W2b  = (const float*)d_in[12];
  const float* b2b  = (const float*)d_in[13];
  const float* Wih_f = (const float*)d_in[14];
  const float* Whh_f = (const float*)d_in[15];
  const float* bih_f = (const float*)d_in[16];
  const float* bhh_f = (const float*)d_in[17];
  const float* Wih_b = (const float*)d_in[18];
  const float* Whh_b = (const float*)d_in[19];
  const float* bih_b = (const float*)d_in[20];
  const float* bhh_b = (const float*)d_in[21];
  const float* Watt = (const float*)d_in[22];
  const float* batt = (const float*)d_in[23];
  const float* Wlin = (const float*)d_in[24];
  const float* blin = (const float*)d_in[25];
  const float* Wfc1 = (const float*)d_in[26];
  const float* bfc1 = (const float*)d_in[27];
  const float* Wfc2 = (const float*)d_in[28];
  const float* bfc2 = (const float*)d_in[29];
  float* out = (float*)d_out;

  const int N = in_sizes[0] / 128;
  const int E = in_sizes[1] / 2;
  const int* src = ei;
  const int* dst = ei + E;

  uint8_t* w8 = (uint8_t*)d_ws;
  size_t off = 0;
  auto alloc = [&](size_t bytes) -> void* {
    void* p = w8 + off;
    off = (off + bytes + 255) & ~(size_t)255;
    return p;
  };
  int*    deg    = (int*)   alloc((size_t)N*4);
  int*    fill   = (int*)   alloc((size_t)N*4);
  int*    indptr = (int*)   alloc(((size_t)N+1)*4);
  int*    col    = (int*)   alloc((size_t)E*4);
  int*    bsum   = (int*)   alloc(2048);
  int*    boffs  = (int*)   alloc(2048);
  float*  h1     = (float*) alloc((size_t)N*64*4);
  float*  h2     = (float*) alloc((size_t)N*64*4);
  float*  h3     = (float*) alloc((size_t)N*64*4);
  float*  aF     = (float*) alloc((size_t)3*N*4);
  float*  aB     = (float*) alloc((size_t)3*N*4);
  float*  vbuf   = (float*) alloc((size_t)N*4);
  double* part   = (double*)alloc(256*8);
  u16*    Wpf    = (u16*)   alloc((size_t)10*12*64*8*2);
  u16*    Wpb    = (u16*)   alloc((size_t)10*12*64*8*2);
  float4* Bpf    = (float4*)alloc((size_t)96*16);
  float4* Bpb    = (float4*)alloc((size_t)96*16);
  float*  P      = (float*) alloc((size_t)N*192*4);
  if (off > ws_size) return;
  float* ybuf = P;
  float* zbuf = P + (size_t)N*64;

  const size_t lds64  = 64  * 102 * 4;
  const size_t lds128 = 128 * 102 * 4;

  hipMemsetAsync(deg,  0, (size_t)N*4, stream);
  hipMemsetAsync(fill, 0, (size_t)N*4, stream);

  int gE = (E + 255) / 256;
  int nb1 = (N + 255) / 256;
  int gG = (N + 63) / 64;
  int gA = (N + 15) / 16;
  int gL = (N + 31) / 32;

  // weight prepack (independent of CSR)
  k_packW2<<<240, 256, 0, stream>>>(Wih_f, Whh_f, Wpf);
  k_packW2<<<240, 256, 0, stream>>>(Wih_b, Whh_b, Wpb);
  k_packB<<<1, 128, 0, stream>>>(bih_f, bhh_f, Bpf);
  k_packB<<<1, 128, 0, stream>>>(bih_b, bhh_b, Bpb);

  k_deg  <<<gE, 256, 0, stream>>>(dst, deg, E);
  k_scan1<<<nb1, 256, 0, stream>>>(deg, indptr, bsum, N);
  k_scan2<<<1, 512, 0, stream>>>(bsum, boffs, indptr, nb1, N);
  k_scan3<<<nb1, 256, 0, stream>>>(indptr, boffs, N);
  k_fill <<<gE, 256, 0, stream>>>(src, dst, indptr, fill, col, E);

  // ---- GIN layer 0 (transform-first: (x+aggX)@W = y+aggY) ----
  k_gemm<<<gG, TPB, lds128, stream>>>(x, W0a, nullptr, ybuf, 128, 64, 0, N);
  k_agg<64><<<gA, 256, 0, stream>>>(ybuf, indptr, col, b0a, zbuf, N);
  k_gemm<<<gG, TPB, lds64, stream>>>(zbuf, W0b, b0b, h1, 64, 64, 1, N);
  // ---- GIN layer 1 ----
  k_gemm<<<gG, TPB, lds64, stream>>>(h1, W1a, nullptr, ybuf, 64, 64, 0, N);
  k_agg<64><<<gA, 256, 0, stream>>>(ybuf, indptr, col, b1a, zbuf, N);
  k_gemm<<<gG, TPB, lds64, stream>>>(zbuf, W1b, b1b, h2, 64, 64, 1, N);
  // ---- GIN layer 2 ----
  k_gemm<<<gG, TPB, lds64, stream>>>(h2, W2a, nullptr, ybuf, 64, 64, 0, N);
  k_agg<64><<<gA, 256, 0, stream>>>(ybuf, indptr, col, b2a, zbuf, N);
  k_gemm<<<gG, TPB, lds64, stream>>>(zbuf, W2b, b2b, h3, 64, 64, 1, N);

  // ---- LSTM: both directions in one dispatch ----
  k_lstm6<<<2*gL, 256, 0, stream>>>(h1, h2, h3, Wpf, Wpb, Bpf, Bpb, Watt, batt,
                                    aF, aB, gL, N);

  // ---- JK attention + linear + fc1 + leaky ----
  k_jk<<<(N+63)/64, 256, 0, stream>>>(aF, aB, h1, h2, h3, Wlin, blin, Wfc1, bfc1, vbuf, N);

  // ---- final dot ----
  k_final1<<<256, 256, 0, stream>>>(Wfc2, vbuf, part, N);
  k_final2<<<1, 256, 0, stream>>>(part, bfc2, out);
}